// Round 10
// baseline (815.973 us; speedup 1.0000x reference)
//
#include <hip/hip_runtime.h>
#include <hip/hip_bf16.h>

#define B_ROWS   524288
#define MEL_BINS 128
#define DIM      64
#define KCODES   128

// ---------------- workspace layout (floats) ----------------
// WT  [128*64]    : W_in^T, WT[j*64+d] = W_in[d*128+j]
// c0T [64*128]    : cb0^T, c0T[d*128+k] = cb0[k*64+d]
// c1T [64*128]    : cb1^T
// n0,n1 [128]     : np pairwise ||c_k||^2
// T0,T1 [128*128] : cb @ W_out^T
#define WS_WT  0
#define WS_C0T (WS_WT + MEL_BINS*DIM)       // 8192
#define WS_C1T (WS_C0T + DIM*KCODES)        // 16384
#define WS_N0  (WS_C1T + DIM*KCODES)        // 24576
#define WS_N1  (WS_N0 + KCODES)             // 24704
#define WS_T0  (WS_N1 + KCODES)             // 24832
#define WS_T1  (WS_T0 + KCODES*MEL_BINS)    // 41216
#define WS_TOT (WS_T1 + KCODES*MEL_BINS)    // 57600 floats

// numpy pairwise_sum (scalar path) emulation for n=64 of v[d]*v[d].
__device__ __forceinline__ float np_pairwise64_sq(const float* v) {
#pragma clang fp contract(off)
    float r0 = v[0]*v[0], r1 = v[1]*v[1], r2 = v[2]*v[2], r3 = v[3]*v[3];
    float r4 = v[4]*v[4], r5 = v[5]*v[5], r6 = v[6]*v[6], r7 = v[7]*v[7];
#pragma unroll
    for (int i = 8; i < 64; i += 8) {
        r0 += v[i+0]*v[i+0]; r1 += v[i+1]*v[i+1];
        r2 += v[i+2]*v[i+2]; r3 += v[i+3]*v[i+3];
        r4 += v[i+4]*v[i+4]; r5 += v[i+5]*v[i+5];
        r6 += v[i+6]*v[i+6]; r7 += v[i+7]*v[i+7];
    }
    return ((r0 + r1) + (r2 + r3)) + ((r4 + r5) + (r6 + r7));
}

__global__ __launch_bounds__(256) void rvq_precomp(
    const float* __restrict__ W_in, const float* __restrict__ cb0,
    const float* __restrict__ cb1, const float* __restrict__ W_out,
    float* __restrict__ ws)
{
#pragma clang fp contract(off)
    float* WT  = ws + WS_WT;
    float* c0T = ws + WS_C0T;
    float* c1T = ws + WS_C1T;
    float* n0  = ws + WS_N0;
    float* n1  = ws + WS_N1;
    float* T0  = ws + WS_T0;
    float* T1  = ws + WS_T1;

    int tid = blockIdx.x * 256 + threadIdx.x;
    if (tid < 16384) {                       // T0[i][m] (mel path: loose threshold)
        int i = tid >> 7, m = tid & 127;
        double a = 0.0;
        for (int d = 0; d < DIM; ++d)
            a = fma((double)cb0[i*DIM + d], (double)W_out[m*DIM + d], a);
        T0[tid] = (float)a;
    } else if (tid < 32768) {                // T1[i][m]
        int t = tid - 16384;
        int i = t >> 7, m = t & 127;
        double a = 0.0;
        for (int d = 0; d < DIM; ++d)
            a = fma((double)cb1[i*DIM + d], (double)W_out[m*DIM + d], a);
        T1[t] = (float)a;
    } else if (tid < 40960) {                // WT[j][d] = W_in[d][j]
        int t = tid - 32768;
        int j = t >> 6, d = t & 63;
        WT[t] = W_in[d*MEL_BINS + j];
    } else if (tid < 41216) {                // n0 / n1 (exact np pairwise)
        int t = tid - 40960;
        const float* cb = (t & 128) ? cb1 : cb0;
        float*       nn = (t & 128) ? n1  : n0;
        int k = t & 127;
        nn[k] = np_pairwise64_sq(cb + k*DIM);
    } else if (tid < 49408) {                // c0T[d][k] = cb0[k][d]
        int t = tid - 41216;
        int d = t >> 7, k = t & 127;
        c0T[t] = cb0[k*DIM + d];
    } else if (tid < 57600) {                // c1T[d][k] = cb1[k][d]
        int t = tid - 49408;
        int d = t >> 7, k = t & 127;
        c1T[t] = cb1[k*DIM + d];
    }
}

// 1 row/thread. AGPR-tolerant structure: z[] is written once per 16-d block
// in the GEMM and read once per 16 FMAs in the dot loops (d-outer, acc[16]).
// ALL z/acc indexing is compile-time static (R6's scratch bug fixed).
// PER-VALUE FP OP ORDER IS BIT-IDENTICAL to the R3-verified np-f32
// emulation (z_d: ascending-j chain; dot_k: ascending-d single accumulator;
// np pairwise squares; first-min strict <) — DO NOT REORDER.
__global__ __launch_bounds__(256) void rvq_main(
    const float* __restrict__ mel,
    const float* __restrict__ b_in,
    const float* __restrict__ cb0,
    const float* __restrict__ cb1,
    const float* __restrict__ b_out,
    const float* __restrict__ ws,
    float* __restrict__ out_mel,
    float* __restrict__ out_idx)
{
#pragma clang fp contract(off)
    const float* __restrict__ WT  = ws + WS_WT;
    const float* __restrict__ c0T = ws + WS_C0T;
    const float* __restrict__ c1T = ws + WS_C1T;
    const float* __restrict__ n0  = ws + WS_N0;
    const float* __restrict__ n1  = ws + WS_N1;
    const float* __restrict__ T0  = ws + WS_T0;
    const float* __restrict__ T1  = ws + WS_T1;

    const int b = blockIdx.x * 256 + threadIdx.x;
    const float4* melr = reinterpret_cast<const float4*>(mel + (size_t)b * MEL_BINS);

    float z[DIM];                 // cold storage (AGPR-friendly: write-once/read-rare)
    float r8[8];                  // np pairwise square accumulators
#pragma unroll
    for (int t = 0; t < 8; ++t) r8[t] = 0.f;

    // ---- z = mel @ W_in^T + b_in, in 4 sequential d-blocks of 16.
    // Per z_d: ascending-j fused chain (j = jc*4 + {0,1,2,3}), frozen order.
#pragma unroll
    for (int db = 0; db < 4; ++db) {
        float zz[16];             // hot accumulators (VGPR-sized working set)
#pragma unroll
        for (int t = 0; t < 16; ++t) zz[t] = 0.f;

        for (int jc = 0; jc < 32; ++jc) {
            float4 m4 = melr[jc];                        // L1-hot on re-reads
            const float* w = WT + jc * 4 * DIM + db * 16; // wave-uniform
#pragma unroll
            for (int t = 0; t < 16; ++t) zz[t] = fmaf(w[t],         m4.x, zz[t]);
#pragma unroll
            for (int t = 0; t < 16; ++t) zz[t] = fmaf(w[DIM + t],   m4.y, zz[t]);
#pragma unroll
            for (int t = 0; t < 16; ++t) zz[t] = fmaf(w[2*DIM + t], m4.z, zz[t]);
#pragma unroll
            for (int t = 0; t < 16; ++t) zz[t] = fmaf(w[3*DIM + t], m4.w, zz[t]);
        }
#pragma unroll
        for (int t = 0; t < 16; ++t) {
            float v = zz[t] + b_in[db*16 + t];   // separate rounded bias add
            z[db*16 + t] = v;                    // park (static index)
            r8[t & 7] += v * v;                  // i ascending per mod-8 lane ✓
        }
        asm volatile("" ::: "memory");           // no load CSE/hoist across blocks
    }
    float sum_rr = ((r8[0] + r8[1]) + (r8[2] + r8[3])) + ((r8[4] + r8[5]) + (r8[6] + r8[7]));

    // ================= codebook 0: d-outer, 16 k-chains per chunk =================
    float best0 = 3.4e38f; int i0 = 0;
    for (int kc = 0; kc < KCODES; kc += 16) {    // rolled chunk loop
        float acc[16];
#pragma unroll
        for (int t = 0; t < 16; ++t) acc[t] = 0.f;
#pragma unroll
        for (int d = 0; d < DIM; ++d) {          // FULL unroll: z[d] static
            const float* cp = c0T + d * KCODES + kc;   // wave-uniform 64 B
            float zd = z[d];                     // one z read per 16 FMAs
#pragma unroll
            for (int t = 0; t < 16; ++t) acc[t] = fmaf(cp[t], zd, acc[t]);
        }
        const float* nk = n0 + kc;
#pragma unroll
        for (int t = 0; t < 16; ++t) {
            float dist = (sum_rr - 2.0f*acc[t]) + nk[t];
            if (dist < best0) { best0 = dist; i0 = kc + t; }  // ascending k, strict <
        }
    }

    // ---- residual = z - cb0[i0] : elementwise rounded sub (per-lane gather)
    {
        const float* c = cb0 + (size_t)i0 * DIM;
#pragma unroll
        for (int d = 0; d < DIM; ++d) z[d] = z[d] - c[d];
    }

    // ---- sum_rr' : np pairwise on residual (frozen order)
#pragma unroll
    for (int t = 0; t < 8; ++t) r8[t] = 0.f;
#pragma unroll
    for (int i = 0; i < 64; i += 8) {
#pragma unroll
        for (int t = 0; t < 8; ++t) r8[t] += z[i + t] * z[i + t];
    }
    sum_rr = ((r8[0] + r8[1]) + (r8[2] + r8[3])) + ((r8[4] + r8[5]) + (r8[6] + r8[7]));

    // ================= codebook 1 =================
    float best1 = 3.4e38f; int i1 = 0;
    for (int kc = 0; kc < KCODES; kc += 16) {
        float acc[16];
#pragma unroll
        for (int t = 0; t < 16; ++t) acc[t] = 0.f;
#pragma unroll
        for (int d = 0; d < DIM; ++d) {
            const float* cp = c1T + d * KCODES + kc;
            float zd = z[d];
#pragma unroll
            for (int t = 0; t < 16; ++t) acc[t] = fmaf(cp[t], zd, acc[t]);
        }
        const float* nk = n1 + kc;
#pragma unroll
        for (int t = 0; t < 16; ++t) {
            float dist = (sum_rr - 2.0f*acc[t]) + nk[t];
            if (dist < best1) { best1 = dist; i1 = kc + t; }
        }
    }

    // ---- decode: out = T0[i0] + T1[i1] + b_out
    const float4* t0r = reinterpret_cast<const float4*>(T0 + (size_t)i0 * MEL_BINS);
    const float4* t1r = reinterpret_cast<const float4*>(T1 + (size_t)i1 * MEL_BINS);
    float4* outr = reinterpret_cast<float4*>(out_mel + (size_t)b * MEL_BINS);
#pragma unroll 4
    for (int q = 0; q < MEL_BINS / 4; ++q) {
        float4 a = t0r[q], c = t1r[q];
        float4 o;
        o.x = a.x + c.x + b_out[4*q + 0];
        o.y = a.y + c.y + b_out[4*q + 1];
        o.z = a.z + c.z + b_out[4*q + 2];
        o.w = a.w + c.w + b_out[4*q + 3];
        outr[q] = o;
    }

    out_idx[2*(size_t)b + 0] = (float)i0;
    out_idx[2*(size_t)b + 1] = (float)i1;
}

extern "C" void kernel_launch(void* const* d_in, const int* in_sizes, int n_in,
                              void* d_out, int out_size, void* d_ws, size_t ws_size,
                              hipStream_t stream)
{
    const float* mel   = (const float*)d_in[0];
    const float* W_in  = (const float*)d_in[1];
    const float* b_in  = (const float*)d_in[2];
    const float* cb0   = (const float*)d_in[3];
    const float* cb1   = (const float*)d_in[4];
    const float* W_out = (const float*)d_in[5];
    const float* b_out = (const float*)d_in[6];

    float* ws      = (float*)d_ws;                 // 230400 bytes used
    float* out_mel = (float*)d_out;
    float* out_idx = (float*)d_out + (size_t)B_ROWS * MEL_BINS;

    rvq_precomp<<<(WS_TOT + 255) / 256, 256, 0, stream>>>(W_in, cb0, cb1, W_out, ws);
    rvq_main<<<B_ROWS / 256, 256, 0, stream>>>(mel, b_in, cb0, cb1, b_out, ws,
                                               out_mel, out_idx);
}

// Round 11
// 570.099 us; speedup vs baseline: 1.4313x; 1.4313x over previous
//
#include <hip/hip_runtime.h>
#include <hip/hip_bf16.h>

#define B_ROWS   524288
#define MEL_BINS 128
#define DIM      64
#define KCODES   128

// ---------------- workspace layout (floats) ----------------
// WT [128*64] : W_in^T, WT[j*64+d] = W_in[d*128+j]
// n0,n1 [128] : np pairwise ||c_k||^2
// T0,T1 [128*128] : cb @ W_out^T
#define WS_WT 0
#define WS_N0 (WS_WT + MEL_BINS*DIM)        // 8192
#define WS_N1 (WS_N0 + KCODES)              // 8320
#define WS_T0 (WS_N1 + KCODES)              // 8448
#define WS_T1 (WS_T0 + KCODES*MEL_BINS)     // 24832
#define WS_TOT (WS_T1 + KCODES*MEL_BINS)    // 41216 floats

// numpy pairwise_sum (scalar path) emulation for n=64 of v[d]*v[d].
__device__ __forceinline__ float np_pairwise64_sq(const float* v) {
#pragma clang fp contract(off)
    float r0 = v[0]*v[0], r1 = v[1]*v[1], r2 = v[2]*v[2], r3 = v[3]*v[3];
    float r4 = v[4]*v[4], r5 = v[5]*v[5], r6 = v[6]*v[6], r7 = v[7]*v[7];
#pragma unroll
    for (int i = 8; i < 64; i += 8) {
        r0 += v[i+0]*v[i+0]; r1 += v[i+1]*v[i+1];
        r2 += v[i+2]*v[i+2]; r3 += v[i+3]*v[i+3];
        r4 += v[i+4]*v[i+4]; r5 += v[i+5]*v[i+5];
        r6 += v[i+6]*v[i+6]; r7 += v[i+7]*v[i+7];
    }
    return ((r0 + r1) + (r2 + r3)) + ((r4 + r5) + (r6 + r7));
}

__global__ __launch_bounds__(256) void rvq_precomp(
    const float* __restrict__ W_in, const float* __restrict__ cb0,
    const float* __restrict__ cb1, const float* __restrict__ W_out,
    float* __restrict__ ws)
{
#pragma clang fp contract(off)
    float* WT = ws + WS_WT;
    float* n0 = ws + WS_N0;
    float* n1 = ws + WS_N1;
    float* T0 = ws + WS_T0;
    float* T1 = ws + WS_T1;

    int tid = blockIdx.x * 256 + threadIdx.x;
    if (tid < 16384) {                       // T0[i][m] (mel path: loose threshold)
        int i = tid >> 7, m = tid & 127;
        double a = 0.0;
        for (int d = 0; d < DIM; ++d)
            a = fma((double)cb0[i*DIM + d], (double)W_out[m*DIM + d], a);
        T0[tid] = (float)a;
    } else if (tid < 32768) {                // T1[i][m]
        int t = tid - 16384;
        int i = t >> 7, m = t & 127;
        double a = 0.0;
        for (int d = 0; d < DIM; ++d)
            a = fma((double)cb1[i*DIM + d], (double)W_out[m*DIM + d], a);
        T1[t] = (float)a;
    } else if (tid < 40960) {                // WT[j][d] = W_in[d][j]
        int t = tid - 32768;
        int j = t >> 6, d = t & 63;
        WT[t] = W_in[d*MEL_BINS + j];
    } else if (tid < 41216) {                // n0 / n1 (exact np pairwise)
        int t = tid - 40960;
        const float* cb = (t & 128) ? cb1 : cb0;
        float*       nn = (t & 128) ? n1  : n0;
        int k = t & 127;
        nn[k] = np_pairwise64_sq(cb + k*DIM);
    }
}

// 1 row/thread. Identical FP structure to the verified R3 kernel; the ONLY
// change is transport: WT / cb0 / cb1 are staged into one 32 KB LDS buffer
// (phase-reused) and all hot-loop table reads are wave-uniform ds_read_b128
// broadcasts instead of s_load streams that thrash the 16 KB scalar cache.
// PER-VALUE FP OP ORDER IS BIT-IDENTICAL — DO NOT REORDER.
__global__ __launch_bounds__(256) void rvq_main(
    const float* __restrict__ mel,
    const float* __restrict__ b_in,
    const float* __restrict__ cb0,
    const float* __restrict__ cb1,
    const float* __restrict__ b_out,
    const float* __restrict__ ws,
    float* __restrict__ out_mel,
    float* __restrict__ out_idx)
{
#pragma clang fp contract(off)
    const float* __restrict__ n0 = ws + WS_N0;
    const float* __restrict__ n1 = ws + WS_N1;
    const float* __restrict__ T0 = ws + WS_T0;
    const float* __restrict__ T1 = ws + WS_T1;

    __shared__ float slds[8192];             // 32 KB staged table (WT -> cb0 -> cb1)
    float4* s4 = reinterpret_cast<float4*>(slds);
    const float4* s4c = reinterpret_cast<const float4*>(slds);

    const int tid = threadIdx.x;
    const int b = blockIdx.x * 256 + tid;

    // ---- stage WT (8192 floats) ----
    {
        const float4* src = reinterpret_cast<const float4*>(ws + WS_WT);
#pragma unroll
        for (int i = 0; i < 8; ++i) s4[i*256 + tid] = src[i*256 + tid];
    }
    __syncthreads();

    // ---- z = mel @ W_in^T : ascending-j fmaf chain per d (frozen order)
    float z[DIM];
#pragma unroll
    for (int d = 0; d < DIM; ++d) z[d] = 0.f;

    const float4* melr = reinterpret_cast<const float4*>(mel + (size_t)b * MEL_BINS);
    for (int jc = 0; jc < MEL_BINS / 4; ++jc) {
        float4 m4 = melr[jc];
#pragma unroll
        for (int seg = 0; seg < 4; ++seg) {  // j = jc*4 + seg, ascending ✓
            float mj = (seg == 0) ? m4.x : (seg == 1) ? m4.y : (seg == 2) ? m4.z : m4.w;
            const float4* w4 = s4c + (jc*4 + seg)*16;   // uniform -> broadcast
#pragma unroll
            for (int q = 0; q < 16; ++q) {
                float4 wv = w4[q];
                z[4*q + 0] = fmaf(wv.x, mj, z[4*q + 0]);
                z[4*q + 1] = fmaf(wv.y, mj, z[4*q + 1]);
                z[4*q + 2] = fmaf(wv.z, mj, z[4*q + 2]);
                z[4*q + 3] = fmaf(wv.w, mj, z[4*q + 3]);
            }
        }
    }
#pragma unroll
    for (int d = 0; d < DIM; ++d) z[d] = z[d] + b_in[d];

    // ---- sum_rr (np pairwise, frozen) ----
    float s0 = z[0]*z[0], s1 = z[1]*z[1], s2 = z[2]*z[2], s3 = z[3]*z[3];
    float s4r = z[4]*z[4], s5 = z[5]*z[5], s6 = z[6]*z[6], s7 = z[7]*z[7];
#pragma unroll
    for (int i = 8; i < 64; i += 8) {
        s0 += z[i+0]*z[i+0]; s1 += z[i+1]*z[i+1];
        s2 += z[i+2]*z[i+2]; s3 += z[i+3]*z[i+3];
        s4r += z[i+4]*z[i+4]; s5 += z[i+5]*z[i+5];
        s6 += z[i+6]*z[i+6]; s7 += z[i+7]*z[i+7];
    }
    float sum_rr = ((s0 + s1) + (s2 + s3)) + ((s4r + s5) + (s6 + s7));

    // ---- stage cb0 (already [k][d] row-major = 8192 floats) ----
    __syncthreads();
    {
        const float4* src = reinterpret_cast<const float4*>(cb0);
#pragma unroll
        for (int i = 0; i < 8; ++i) s4[i*256 + tid] = src[i*256 + tid];
    }
    __syncthreads();

    // ================= codebook 0 =================
    float best0 = 3.4e38f; int i0 = 0;
    for (int k = 0; k < KCODES; ++k) {
        const float4* c4 = s4c + k*16;       // uniform -> broadcast ds_read_b128
        float acc = 0.f;
#pragma unroll
        for (int q = 0; q < 16; ++q) {       // ascending d, single accumulator ✓
            float4 cv = c4[q];
            acc = fmaf(cv.x, z[4*q + 0], acc);
            acc = fmaf(cv.y, z[4*q + 1], acc);
            acc = fmaf(cv.z, z[4*q + 2], acc);
            acc = fmaf(cv.w, z[4*q + 3], acc);
        }
        float dist = (sum_rr - 2.0f*acc) + n0[k];
        if (dist < best0) { best0 = dist; i0 = k; }   // strict < = first-min
    }

    // ---- stage cb1 (before residual so ds_writes overlap the global gather)
    __syncthreads();
    {
        const float4* src = reinterpret_cast<const float4*>(cb1);
#pragma unroll
        for (int i = 0; i < 8; ++i) s4[i*256 + tid] = src[i*256 + tid];
    }

    // ---- residual = z - cb0[i0] : per-lane global gather (L2-hot), frozen sub
    {
        const float* c = cb0 + (size_t)i0 * DIM;
#pragma unroll
        for (int d = 0; d < DIM; ++d) z[d] = z[d] - c[d];
    }

    // ---- sum_rr' (np pairwise, frozen) ----
    s0 = z[0]*z[0]; s1 = z[1]*z[1]; s2 = z[2]*z[2]; s3 = z[3]*z[3];
    s4r = z[4]*z[4]; s5 = z[5]*z[5]; s6 = z[6]*z[6]; s7 = z[7]*z[7];
#pragma unroll
    for (int i = 8; i < 64; i += 8) {
        s0 += z[i+0]*z[i+0]; s1 += z[i+1]*z[i+1];
        s2 += z[i+2]*z[i+2]; s3 += z[i+3]*z[i+3];
        s4r += z[i+4]*z[i+4]; s5 += z[i+5]*z[i+5];
        s6 += z[i+6]*z[i+6]; s7 += z[i+7]*z[i+7];
    }
    sum_rr = ((s0 + s1) + (s2 + s3)) + ((s4r + s5) + (s6 + s7));

    __syncthreads();

    // ================= codebook 1 =================
    float best1 = 3.4e38f; int i1 = 0;
    for (int k = 0; k < KCODES; ++k) {
        const float4* c4 = s4c + k*16;
        float acc = 0.f;
#pragma unroll
        for (int q = 0; q < 16; ++q) {
            float4 cv = c4[q];
            acc = fmaf(cv.x, z[4*q + 0], acc);
            acc = fmaf(cv.y, z[4*q + 1], acc);
            acc = fmaf(cv.z, z[4*q + 2], acc);
            acc = fmaf(cv.w, z[4*q + 3], acc);
        }
        float dist = (sum_rr - 2.0f*acc) + n1[k];
        if (dist < best1) { best1 = dist; i1 = k; }
    }

    // ---- decode: out = T0[i0] + T1[i1] + b_out
    const float4* t0r = reinterpret_cast<const float4*>(T0 + (size_t)i0 * MEL_BINS);
    const float4* t1r = reinterpret_cast<const float4*>(T1 + (size_t)i1 * MEL_BINS);
    float4* outr = reinterpret_cast<float4*>(out_mel + (size_t)b * MEL_BINS);
#pragma unroll 4
    for (int q = 0; q < MEL_BINS / 4; ++q) {
        float4 a = t0r[q], c = t1r[q];
        float4 o;
        o.x = a.x + c.x + b_out[4*q + 0];
        o.y = a.y + c.y + b_out[4*q + 1];
        o.z = a.z + c.z + b_out[4*q + 2];
        o.w = a.w + c.w + b_out[4*q + 3];
        outr[q] = o;
    }

    out_idx[2*(size_t)b + 0] = (float)i0;
    out_idx[2*(size_t)b + 1] = (float)i1;
}

extern "C" void kernel_launch(void* const* d_in, const int* in_sizes, int n_in,
                              void* d_out, int out_size, void* d_ws, size_t ws_size,
                              hipStream_t stream)
{
    const float* mel   = (const float*)d_in[0];
    const float* W_in  = (const float*)d_in[1];
    const float* b_in  = (const float*)d_in[2];
    const float* cb0   = (const float*)d_in[3];
    const float* cb1   = (const float*)d_in[4];
    const float* W_out = (const float*)d_in[5];
    const float* b_out = (const float*)d_in[6];

    float* ws      = (float*)d_ws;                 // 164864 bytes used
    float* out_mel = (float*)d_out;
    float* out_idx = (float*)d_out + (size_t)B_ROWS * MEL_BINS;

    rvq_precomp<<<(WS_TOT + 255) / 256, 256, 0, stream>>>(W_in, cb0, cb1, W_out, ws);
    rvq_main<<<B_ROWS / 256, 256, 0, stream>>>(mel, b_in, cb0, cb1, b_out, ws,
                                               out_mel, out_idx);
}